// Round 2
// baseline (113.257 us; speedup 1.0000x reference)
//
#include <hip/hip_runtime.h>
#include <math.h>

#define BB 524288
#define CC 10
#define TT 25
#define BLK 256
#define SLAB (BLK * CC)          // 2560 floats = one t-slab for the block
#define HALF (SLAB / 2)          // 1280 floats = one wave-pair half

// global_load_lds dwordx4: LDS dest = wave-uniform base + lane*16; global src per-lane.
#define GLL16(src, dst)                                                     \
    __builtin_amdgcn_global_load_lds(                                       \
        (const __attribute__((address_space(1))) void*)(src),               \
        (__attribute__((address_space(3))) void*)(dst), 16, 0, 0)

__global__ void init_out_kernel(float* out) {
    // output = logT - (1/B) * sum_b (M_b + log S_b)
    *out = logf((float)TT);
}

__global__ __launch_bounds__(256) void mc_nll_kernel(
    const float* __restrict__ mu,
    const float* __restrict__ ls2,
    const int*   __restrict__ y,
    const float* __restrict__ eps,
    float* __restrict__ out)
{
    // Two ping-pong slabs, each holding TWO t-slabs (2*2560 floats = 20 KB). 40 KB total.
    __shared__ float lds[2][2 * SLAB];
    __shared__ float wsum[4];

    const int tid  = threadIdx.x;
    const int wid  = tid >> 6;
    const int lane = tid & 63;
    const int G    = blockIdx.x * BLK;   // first b of this block
    const int b    = G + tid;

    const int yi = y[b];                 // issued early; compiler waits before use

    // ---- prologue stage 1: mu (waves 0,1) / ls2 (waves 2,3) into lds[1] ----
    {
        const float* base = (wid >> 1) ? ls2 : mu;
        const float* src  = base + (size_t)G * CC + (wid & 1) * HALF + lane * 4;
        float*       dst  = &lds[1][(wid >> 1) * SLAB + (wid & 1) * HALF];
#pragma unroll
        for (int j = 0; j < 5; ++j)
            GLL16(src + j * 256, dst + j * 256);
    }

    // ---- prologue stage 2: t-pair 0 into lds[0] ----
    // wave pair (wid>>1) picks t; (wid&1) picks the half of the 2560-float slab
    {
        const int t = (wid >> 1);
        const float* src = eps + ((size_t)t * BB + G) * CC + (wid & 1) * HALF + lane * 4;
        float*       dst = &lds[0][(wid >> 1) * SLAB + (wid & 1) * HALF];
#pragma unroll
        for (int j = 0; j < 5; ++j)
            GLL16(src + j * 256, dst + j * 256);
    }

    // my first 5 loads (mu/ls2) complete; pair-0 loads may stay in flight
    asm volatile("s_waitcnt vmcnt(5)" ::: "memory");
    __builtin_amdgcn_s_barrier();

    // ---- read mu/ls2 from LDS, build per-b params in registers ----
    float muv[CC], sig[CC];
    {
        const float* mrow = &lds[1][tid * CC];
        const float* srow = &lds[1][SLAB + tid * CC];
#pragma unroll
        for (int i = 0; i < CC / 2; ++i) {
            float2 m2 = *reinterpret_cast<const float2*>(mrow + 2 * i);
            float2 s2 = *reinterpret_cast<const float2*>(srow + 2 * i);
            muv[2 * i]     = m2.x;
            muv[2 * i + 1] = m2.y;
            sig[2 * i]     = __expf(0.5f * s2.x);
            sig[2 * i + 1] = __expf(0.5f * s2.y);
        }
    }
    // my ds_reads of lds[1] done before anyone overwrites it (loop p=0 stages into lds[1])
    asm volatile("s_waitcnt lgkmcnt(0)" ::: "memory");
    __builtin_amdgcn_s_barrier();

    // ---- pipelined main loop over 12 t-pairs (t = 0..23) ----
    float M = -INFINITY, S = 0.0f;
    int buf = 0;
    for (int p = 0; p < 12; ++p) {
        if (p < 11) {
            // prefetch pair p+1 into the other buffer
            const int t = 2 * (p + 1) + (wid >> 1);
            const float* src = eps + ((size_t)t * BB + G) * CC + (wid & 1) * HALF + lane * 4;
            float*       dst = &lds[buf ^ 1][(wid >> 1) * SLAB + (wid & 1) * HALF];
#pragma unroll
            for (int j = 0; j < 5; ++j)
                GLL16(src + j * 256, dst + j * 256);
            asm volatile("s_waitcnt vmcnt(5)" ::: "memory");  // pair-p loads done; p+1 in flight
        } else {
            asm volatile("s_waitcnt vmcnt(0)" ::: "memory");
        }
        __builtin_amdgcn_s_barrier();

#pragma unroll
        for (int ti = 0; ti < 2; ++ti) {
            const float* row = &lds[buf][ti * SLAB + tid * CC];
            float l[CC];
#pragma unroll
            for (int i = 0; i < CC / 2; ++i) {
                float2 e = *reinterpret_cast<const float2*>(row + 2 * i);
                l[2 * i]     = fmaf(sig[2 * i],     e.x, muv[2 * i]);
                l[2 * i + 1] = fmaf(sig[2 * i + 1], e.y, muv[2 * i + 1]);
            }
            float m = -INFINITY, ly = 0.0f;
#pragma unroll
            for (int c = 0; c < CC; ++c) {
                m = fmaxf(m, l[c]);
                ly = (c == yi) ? l[c] : ly;
            }
            float s = 0.0f;
#pragma unroll
            for (int c = 0; c < CC; ++c) s += __expf(l[c] - m);
            const float v = ly - (m + __logf(s));

            const float nm = fmaxf(M, v);
            S = S * __expf(M - nm) + __expf(v - nm);
            M = nm;
        }

        // my LDS reads of lds[buf] drained before next iteration overwrites it
        asm volatile("s_waitcnt lgkmcnt(0)" ::: "memory");
        __builtin_amdgcn_s_barrier();
        buf ^= 1;
    }

    // ---- tail: t = 24, direct global loads (1/25 of traffic) ----
    {
        const float2* e2 = reinterpret_cast<const float2*>(
            eps + ((size_t)24 * BB + (size_t)b) * CC);
        float l[CC];
#pragma unroll
        for (int i = 0; i < CC / 2; ++i) {
            float2 e = e2[i];
            l[2 * i]     = fmaf(sig[2 * i],     e.x, muv[2 * i]);
            l[2 * i + 1] = fmaf(sig[2 * i + 1], e.y, muv[2 * i + 1]);
        }
        float m = -INFINITY, ly = 0.0f;
#pragma unroll
        for (int c = 0; c < CC; ++c) {
            m = fmaxf(m, l[c]);
            ly = (c == yi) ? l[c] : ly;
        }
        float s = 0.0f;
#pragma unroll
        for (int c = 0; c < CC; ++c) s += __expf(l[c] - m);
        const float v = ly - (m + __logf(s));
        const float nm = fmaxf(M, v);
        S = S * __expf(M - nm) + __expf(v - nm);
        M = nm;
    }
    const float picked_no_logT = M + __logf(S);

    // ---- block reduction: wave shuffle -> LDS -> one atomic per block ----
    float x = picked_no_logT;
#pragma unroll
    for (int off = 32; off > 0; off >>= 1)
        x += __shfl_down(x, off, 64);

    if (lane == 0) wsum[wid] = x;
    __syncthreads();
    if (tid == 0) {
        float bs = wsum[0] + wsum[1] + wsum[2] + wsum[3];
        atomicAdd(out, -bs * (1.0f / (float)BB));
    }
}

extern "C" void kernel_launch(void* const* d_in, const int* in_sizes, int n_in,
                              void* d_out, int out_size, void* d_ws, size_t ws_size,
                              hipStream_t stream) {
    const float* mu  = (const float*)d_in[0];
    const float* ls2 = (const float*)d_in[1];
    const int*   y   = (const int*)d_in[2];
    const float* eps = (const float*)d_in[3];
    float* out = (float*)d_out;

    hipLaunchKernelGGL(init_out_kernel, dim3(1), dim3(1), 0, stream, out);
    hipLaunchKernelGGL(mc_nll_kernel, dim3(BB / BLK), dim3(BLK), 0, stream,
                       mu, ls2, y, eps, out);
}